// Round 3
// baseline (74.153 us; speedup 1.0000x reference)
//
#include <hip/hip_runtime.h>

#define DENSE 2048
#define BATCH 64
#define MAXS  1024

typedef __attribute__((ext_vector_type(8))) __bf16 bf16x8;
typedef __attribute__((ext_vector_type(4))) float f32x4;

// ws layout: Cbf[b][k] (bf16 counts) stored in MFMA A-fragment order so spmm's
// A-frag load is one coalesced global_load_dwordx4 per lane:
//   lane = (b&15) | (((k>>3)&3)<<4) holds C[b = mt*16 + (lane&15)][k = ks*32 + (lane>>4)*8 + i]
// which is exactly A[m=lane&15][k=(lane>>4)*8+i] for mfma_f32_16x16x32_bf16.
// Layout verified by round-2 pass (absmax 1.0 vs threshold 5.64).

__global__ __launch_bounds__(256) void hist_kernel(const int* __restrict__ ids,
                                                   const int* __restrict__ ns,
                                                   __bf16* __restrict__ Cbf,
                                                   float* __restrict__ out) {
    __shared__ int cnt[DENSE];
    const int b = blockIdx.x;
    const int tid = threadIdx.x;
    #pragma unroll
    for (int k = tid; k < DENSE; k += 256) cnt[k] = 0;
    __syncthreads();
    const int n = ns[b];
    for (int i = tid; i < n; i += 256) {
        atomicAdd(&cnt[ids[b * MAXS + i]], 1);
    }
    __syncthreads();
    const int mt = b >> 4;
    const int bl = b & 15;
    #pragma unroll
    for (int k = tid; k < DENSE; k += 256) {
        const int lane = bl | (((k >> 3) & 3) << 4);
        const size_t off = (size_t)(((k >> 5) * 4 + mt) * 64 + lane) * 8 + (k & 7);
        Cbf[off] = (__bf16)(float)cnt[k];
        out[(size_t)b * DENSE + k] = 0.0f;   // zero output for spmm's atomics
    }
}

// spmm: out[b][j] += sum_k C[b][k] * W[j][k] via bf16 MFMA 16x16x32.
// grid (128 j-tiles of 16, 4 k-splits of 512), 4 waves/block; wave handles 4
// k-steps. v3 change: ALL 24 global loads (8 W nontemporal + 16 A) issued
// up-front into registers for memory-level parallelism, then cvt, then MFMA.
// __launch_bounds__(256,3): allow ~170 VGPR, no spill, 12 waves/CU.
__global__ __launch_bounds__(256, 3) void spmm_kernel(const float* __restrict__ W,
                                                      const __bf16* __restrict__ Cbf,
                                                      float* __restrict__ out) {
    const int tid  = threadIdx.x;
    const int lane = tid & 63;
    const int wv   = tid >> 6;          // 0..3
    const int j0   = blockIdx.x * 16;   // j tile
    const int ks4  = blockIdx.y;        // 0..3 k split

    const int ln = lane & 15;           // j / m index within tile
    const int lq = lane >> 4;           // k quad 0..3

    const int step0 = ks4 * 16 + wv * 4;
    const float* wrow = W + (size_t)(j0 + ln) * DENSE;

    // --- issue ALL W loads (streaming; W is read exactly once -> nontemporal)
    f32x4 w0[4], w1[4];
    #pragma unroll
    for (int s = 0; s < 4; ++s) {
        const int kbase = (step0 + s) * 32 + lq * 8;
        w0[s] = __builtin_nontemporal_load((const f32x4*)(wrow + kbase));
        w1[s] = __builtin_nontemporal_load((const f32x4*)(wrow + kbase + 4));
    }
    // --- issue ALL A-frag loads (L2-hot, keep cacheable)
    bf16x8 afr[4][4];
    #pragma unroll
    for (int s = 0; s < 4; ++s) {
        #pragma unroll
        for (int mt = 0; mt < 4; ++mt) {
            afr[s][mt] = *(const bf16x8*)(Cbf + ((size_t)((step0 + s) * 4 + mt) * 64 + lane) * 8);
        }
    }

    // --- convert W fp32 -> bf16 fragments (waits on W loads as they arrive)
    bf16x8 wb[4];
    #pragma unroll
    for (int s = 0; s < 4; ++s) {
        #pragma unroll
        for (int i = 0; i < 4; ++i) {
            wb[s][i]     = (__bf16)w0[s][i];
            wb[s][i + 4] = (__bf16)w1[s][i];
        }
    }

    // --- MFMA chain
    f32x4 acc[4];
    #pragma unroll
    for (int mt = 0; mt < 4; ++mt) acc[mt] = (f32x4)0.0f;
    #pragma unroll
    for (int s = 0; s < 4; ++s) {
        #pragma unroll
        for (int mt = 0; mt < 4; ++mt) {
            acc[mt] = __builtin_amdgcn_mfma_f32_16x16x32_bf16(afr[s][mt], wb[s], acc[mt], 0, 0, 0);
        }
    }

    // --- cross-wave reduction, conflict-free layout P[wv][mt][r][lane]
    __shared__ float P[4][4][4][64];    // 16 KB
    #pragma unroll
    for (int mt = 0; mt < 4; ++mt) {
        #pragma unroll
        for (int r = 0; r < 4; ++r) {
            P[wv][mt][r][lane] = acc[mt][r];
        }
    }
    __syncthreads();

    // thread t -> (jloc = t&15 fastest for coalesced atomics, bpart = t>>4)
    const int jloc  = tid & 15;
    const int bpart = tid >> 4;                       // 0..15
    const int lsrc  = ((bpart >> 2) << 4) | jloc;     // source lane
    const int r     = bpart & 3;                      // source acc reg
    #pragma unroll
    for (int mt = 0; mt < 4; ++mt) {
        const float v = P[0][mt][r][lsrc] + P[1][mt][r][lsrc]
                      + P[2][mt][r][lsrc] + P[3][mt][r][lsrc];
        atomicAdd(&out[(size_t)(mt * 16 + bpart) * DENSE + j0 + jloc], v);
    }
}

extern "C" void kernel_launch(void* const* d_in, const int* in_sizes, int n_in,
                              void* d_out, int out_size, void* d_ws, size_t ws_size,
                              hipStream_t stream) {
    const int*   ids = (const int*)d_in[0];   // [64, 1024] int32
    const int*   ns  = (const int*)d_in[1];   // [64] int32
    const float* W   = (const float*)d_in[2]; // [2048, 2048] float32
    float*  out = (float*)d_out;              // [64, 2048] float32
    __bf16* Cbf = (__bf16*)d_ws;              // 64*2048 bf16 = 256 KB

    hipLaunchKernelGGL(hist_kernel, dim3(BATCH), dim3(256), 0, stream, ids, ns, Cbf, out);
    hipLaunchKernelGGL(spmm_kernel, dim3(128, 4), dim3(256), 0, stream, W, Cbf, out);
}